// Round 3
// baseline (620.127 us; speedup 1.0000x reference)
//
#include <hip/hip_runtime.h>

#define SS 2048
#define BB 32
#define DD 1024
#define RB 16   // batch rows per block
#define GT 8    // t-steps per block
#define NW 8    // waves per block

typedef unsigned short u16;
typedef unsigned int u32;
using f32x4 = __attribute__((ext_vector_type(4))) float;
using bf16x8 = __attribute__((ext_vector_type(8))) short;

__device__ __forceinline__ u16 f2bf(float x) {
  union { float f; u32 u; } c; c.f = x;
  u32 r = c.u + 0x7fffu + ((c.u >> 16) & 1u);
  return (u16)(r >> 16);
}
__device__ __forceinline__ float bf2f(u32 h) {
  union { u32 u; float f; } c; c.u = h << 16; return c.f;
}
// XOR swizzle for row-stride-2048B bf16 tiles: spreads cross-row same-col
// ds_read_b128 (A-frag loads) evenly over banks; keeps 16B chunks intact.
__device__ __forceinline__ int swzb(int row, int col) {
  return ((row << 11) + (col << 1)) ^ ((row & 7) << 4);
}
__device__ __forceinline__ void st8(u16* base, int row, int col, float4 a, float4 b) {
  uint4 pk;
  pk.x = (u32)f2bf(a.x) | ((u32)f2bf(a.y) << 16);
  pk.y = (u32)f2bf(a.z) | ((u32)f2bf(a.w) << 16);
  pk.z = (u32)f2bf(b.x) | ((u32)f2bf(b.y) << 16);
  pk.w = (u32)f2bf(b.z) | ((u32)f2bf(b.w) << 16);
  *reinterpret_cast<uint4*>(reinterpret_cast<char*>(base) + swzb(row, col)) = pk;
}
__device__ __forceinline__ void st8z(u16* base, int row, int col) {
  uint4 pk; pk.x = pk.y = pk.z = pk.w = 0u;
  *reinterpret_cast<uint4*>(reinterpret_cast<char*>(base) + swzb(row, col)) = pk;
}
__device__ __forceinline__ uint4 ld16(const u16* base, int row, int col) {
  return *reinterpret_cast<const uint4*>(reinterpret_cast<const char*>(base) + swzb(row, col));
}
__device__ __forceinline__ bf16x8 ld_afrag(const u16* base, int row, int col) {
  return *reinterpret_cast<const bf16x8*>(reinterpret_cast<const char*>(base) + swzb(row, col));
}
// tanh-form GELU, branch-free (v_exp_f32). |err| vs exact < ~3e-4.
__device__ __forceinline__ float gelu_f(float v) {
  const float u2 = 1.5957691216057308f * v * __builtin_fmaf(0.044715f, v * v, 1.0f);
  const float e = __expf(u2);
  const float th = 1.0f - 2.0f * __builtin_amdgcn_rcpf(e + 1.0f);
  return 0.5f * v * (1.0f + th);
}

// LN a 1024-wide row held 16-elems-per-lane across the wave; write bf16 to cbuf.
__device__ __forceinline__ void ln_row_to_c(u16* cbuf, int row, int c0, const float* v,
                                            const float* __restrict__ gamma,
                                            const float* __restrict__ beta) {
  float s1 = 0.f, s2 = 0.f;
#pragma unroll
  for (int j = 0; j < 16; ++j) { s1 += v[j]; s2 += v[j] * v[j]; }
#pragma unroll
  for (int off = 32; off; off >>= 1) { s1 += __shfl_xor(s1, off); s2 += __shfl_xor(s2, off); }
  const float mu = s1 * (1.f / 1024.f);
  const float rs = rsqrtf(s2 * (1.f / 1024.f) - mu * mu + 1e-5f);
  float4 g0 = *reinterpret_cast<const float4*>(gamma + c0);
  float4 g1 = *reinterpret_cast<const float4*>(gamma + c0 + 4);
  float4 g2 = *reinterpret_cast<const float4*>(gamma + 512 + c0);
  float4 g3 = *reinterpret_cast<const float4*>(gamma + 512 + c0 + 4);
  float4 b0 = *reinterpret_cast<const float4*>(beta + c0);
  float4 b1 = *reinterpret_cast<const float4*>(beta + c0 + 4);
  float4 b2 = *reinterpret_cast<const float4*>(beta + 512 + c0);
  float4 b3 = *reinterpret_cast<const float4*>(beta + 512 + c0 + 4);
  float4 o0, o1, o2, o3;
  o0.x = (v[0] - mu) * rs * g0.x + b0.x;   o0.y = (v[1] - mu) * rs * g0.y + b0.y;
  o0.z = (v[2] - mu) * rs * g0.z + b0.z;   o0.w = (v[3] - mu) * rs * g0.w + b0.w;
  o1.x = (v[4] - mu) * rs * g1.x + b1.x;   o1.y = (v[5] - mu) * rs * g1.y + b1.y;
  o1.z = (v[6] - mu) * rs * g1.z + b1.z;   o1.w = (v[7] - mu) * rs * g1.w + b1.w;
  o2.x = (v[8] - mu) * rs * g2.x + b2.x;   o2.y = (v[9] - mu) * rs * g2.y + b2.y;
  o2.z = (v[10] - mu) * rs * g2.z + b2.z;  o2.w = (v[11] - mu) * rs * g2.w + b2.w;
  o3.x = (v[12] - mu) * rs * g3.x + b3.x;  o3.y = (v[13] - mu) * rs * g3.y + b3.y;
  o3.z = (v[14] - mu) * rs * g3.z + b3.z;  o3.w = (v[15] - mu) * rs * g3.w + b3.w;
  st8(cbuf, row, c0, o0, o1);
  st8(cbuf, row, 512 + c0, o2, o3);
}

// Repack W [H][128][64] f32 -> bf16 MFMA B-fragment order (unchanged from R1/R2).
__global__ void prep_w(const float* __restrict__ W, u16* __restrict__ Wf) {
  const int o = blockIdx.x * 256 + threadIdx.x;
  const int l = o & 63;
  const int tile = o >> 6;
  const int nt = tile & 3, ks = (tile >> 2) & 3, h = tile >> 4;
  const int d = nt * 16 + (l & 15);
  const int kbw = ks * 32 + 8 * (l >> 4);
  u16 v[8];
#pragma unroll
  for (int j = 0; j < 8; ++j) v[j] = f2bf(W[(h * 128 + kbw + j) * 64 + d]);
  uint4 pk;
  pk.x = (u32)v[0] | ((u32)v[1] << 16);
  pk.y = (u32)v[2] | ((u32)v[3] << 16);
  pk.z = (u32)v[4] | ((u32)v[5] << 16);
  pk.w = (u32)v[6] | ((u32)v[7] << 16);
  reinterpret_cast<uint4*>(Wf)[o] = pk;
}

__global__ __launch_bounds__(512, 4) void lienet_main(
    const float* __restrict__ src, const u16* __restrict__ Wf,
    const float* __restrict__ bias, const float* __restrict__ gamma,
    const float* __restrict__ beta, float* __restrict__ out) {
  __shared__ __align__(16) u16 cbuf[RB * DD];       // 32 KB
  __shared__ __align__(16) u16 xbuf[RB * DD];       // 32 KB
  __shared__ __align__(16) float part[RB][NW][2];   // 1 KB

  const int bid = blockIdx.x;           // 512 blocks: 256 t-chunks x 2 row-groups
  const int t0 = (bid >> 1) * GT;
  const int rg = bid & 1;

  const int tid = threadIdx.x;
  const int wave = tid >> 6;
  const int lane = tid & 63;
  const int c0 = lane * 8;              // this lane's 8-col chunk per 512-col half
  const int r0 = wave * 2;              // this wave stages tile rows r0, r0+1
  const int kb = 8 * (lane >> 4);
  const int cl = lane & 15;
  const int rq = lane >> 4;             // C-row quarter: rows rq*4 .. rq*4+3

  // -------- prologue: stage x(t0), c(t0) --------
#pragma unroll
  for (int rr = 0; rr < 2; ++rr) {
    const int row = r0 + rr;
    const int grow = rg * RB + row;
    const float* xp = src + ((size_t)t0 * BB + grow) * DD;
    float4 xa = *reinterpret_cast<const float4*>(xp + c0);
    float4 xb = *reinterpret_cast<const float4*>(xp + c0 + 4);
    float4 xc = *reinterpret_cast<const float4*>(xp + 512 + c0);
    float4 xd = *reinterpret_cast<const float4*>(xp + 512 + c0 + 4);
    st8(xbuf, row, c0, xa, xb);
    st8(xbuf, row, 512 + c0, xc, xd);
    if (t0 == 0) {
      st8z(cbuf, row, c0);
      st8z(cbuf, row, 512 + c0);
    } else {
      const float* cp = src + ((size_t)(t0 - 1) * BB + grow) * DD;
      float v[16];
      *reinterpret_cast<float4*>(v + 0)  = *reinterpret_cast<const float4*>(cp + c0);
      *reinterpret_cast<float4*>(v + 4)  = *reinterpret_cast<const float4*>(cp + c0 + 4);
      *reinterpret_cast<float4*>(v + 8)  = *reinterpret_cast<const float4*>(cp + 512 + c0);
      *reinterpret_cast<float4*>(v + 12) = *reinterpret_cast<const float4*>(cp + 512 + c0 + 4);
      ln_row_to_c(cbuf, row, c0, v, gamma, beta);
    }
  }
  f32x4 acc[2][4];
#pragma unroll
  for (int hh = 0; hh < 2; ++hh)
#pragma unroll
    for (int nt = 0; nt < 4; ++nt) acc[hh][nt] = (f32x4){0.f, 0.f, 0.f, 0.f};
  __syncthreads();

  // -------- main loop over t --------
  for (int t = t0; t < t0 + GT; ++t) {
    // phase 1: MFMA  (A from LDS, B from L2-resident Wf)
    __builtin_amdgcn_s_setprio(1);
#pragma unroll
    for (int ks = 0; ks < 4; ++ks) {
      const u16* sb = (ks < 2) ? cbuf : xbuf;   // cat = [c ; x]
#pragma unroll
      for (int hh = 0; hh < 2; ++hh) {
        const int h = wave * 2 + hh;
        bf16x8 afr = ld_afrag(sb, cl, h * 64 + (ks & 1) * 32 + kb);
        const uint4* wp = reinterpret_cast<const uint4*>(Wf) + ((h * 4 + ks) * 4) * 64 + lane;
#pragma unroll
        for (int nt = 0; nt < 4; ++nt) {
          uint4 wv = wp[nt * 64];
          bf16x8 bfr = *reinterpret_cast<bf16x8*>(&wv);
          acc[hh][nt] = __builtin_amdgcn_mfma_f32_16x16x32_bf16(afr, bfr, acc[hh][nt], 0, 0, 0);
        }
      }
    }
    __builtin_amdgcn_s_setprio(0);

    // phase 2: issue x(t+1) prefetch; bias+GELU into acc; per-wave LN partials
    const bool stage = (t + 1 < t0 + GT);
    float4 nx[2][4];
    if (stage) {
#pragma unroll
      for (int rr = 0; rr < 2; ++rr) {
        const float* xp = src + ((size_t)(t + 1) * BB + rg * RB + r0 + rr) * DD;
        nx[rr][0] = *reinterpret_cast<const float4*>(xp + c0);
        nx[rr][1] = *reinterpret_cast<const float4*>(xp + c0 + 4);
        nx[rr][2] = *reinterpret_cast<const float4*>(xp + 512 + c0);
        nx[rr][3] = *reinterpret_cast<const float4*>(xp + 512 + c0 + 4);
      }
    }
#pragma unroll
    for (int hh = 0; hh < 2; ++hh)
#pragma unroll
      for (int nt = 0; nt < 4; ++nt) {
        const float bv = bias[(wave * 2 + hh) * 64 + nt * 16 + cl];
#pragma unroll
        for (int r = 0; r < 4; ++r)
          acc[hh][nt][r] = gelu_f(acc[hh][nt][r] + bv);
      }
#pragma unroll
    for (int r = 0; r < 4; ++r) {
      float a = 0.f, b = 0.f;
#pragma unroll
      for (int hh = 0; hh < 2; ++hh)
#pragma unroll
        for (int nt = 0; nt < 4; ++nt) {
          const float g = acc[hh][nt][r];
          a += g; b += g * g;
        }
      a += __shfl_xor(a, 1); b += __shfl_xor(b, 1);
      a += __shfl_xor(a, 2); b += __shfl_xor(b, 2);
      a += __shfl_xor(a, 4); b += __shfl_xor(b, 4);
      a += __shfl_xor(a, 8); b += __shfl_xor(b, 8);
      if (cl == 0) { part[rq * 4 + r][wave][0] = a; part[rq * 4 + r][wave][1] = b; }
    }
    __syncthreads();  // bar1: LDS A-reads of t done; parts(t) visible

    // phase 4a: stage t+1 — c from bf16 xbuf readback (src read ONCE), x from nx
    if (stage) {
#pragma unroll
      for (int rr = 0; rr < 2; ++rr) {
        const int row = r0 + rr;
        uint4 g0 = ld16(xbuf, row, c0);
        uint4 g1 = ld16(xbuf, row, 512 + c0);
        float v[16];
        v[0] = bf2f(g0.x & 0xffffu);  v[1] = bf2f(g0.x >> 16);
        v[2] = bf2f(g0.y & 0xffffu);  v[3] = bf2f(g0.y >> 16);
        v[4] = bf2f(g0.z & 0xffffu);  v[5] = bf2f(g0.z >> 16);
        v[6] = bf2f(g0.w & 0xffffu);  v[7] = bf2f(g0.w >> 16);
        v[8] = bf2f(g1.x & 0xffffu);  v[9] = bf2f(g1.x >> 16);
        v[10] = bf2f(g1.y & 0xffffu); v[11] = bf2f(g1.y >> 16);
        v[12] = bf2f(g1.z & 0xffffu); v[13] = bf2f(g1.z >> 16);
        v[14] = bf2f(g1.w & 0xffffu); v[15] = bf2f(g1.w >> 16);
        ln_row_to_c(cbuf, row, c0, v, gamma, beta);           // c(t+1) = LN(x(t))
        st8(xbuf, row, c0, nx[rr][0], nx[rr][1]);             // x(t+1)
        st8(xbuf, row, 512 + c0, nx[rr][2], nx[rr][3]);
      }
    }

    // phase 4b: merge LN stats, write out(t), re-zero acc
    float mu[4], rs[4];
#pragma unroll
    for (int r = 0; r < 4; ++r) {
      const float4* pp = reinterpret_cast<const float4*>(&part[rq * 4 + r][0][0]);
      float4 p0 = pp[0], p1 = pp[1], p2 = pp[2], p3 = pp[3];
      const float a = p0.x + p0.z + p1.x + p1.z + p2.x + p2.z + p3.x + p3.z;
      const float b = p0.y + p0.w + p1.y + p1.w + p2.y + p2.w + p3.y + p3.w;
      mu[r] = a * (1.f / 1024.f);
      rs[r] = rsqrtf(b * (1.f / 1024.f) - mu[r] * mu[r] + 1e-5f);
    }
#pragma unroll
    for (int hh = 0; hh < 2; ++hh)
#pragma unroll
      for (int nt = 0; nt < 4; ++nt) {
        const int dcol = (wave * 2 + hh) * 64 + nt * 16 + cl;
        const float eg = gamma[dcol], eb = beta[dcol];
#pragma unroll
        for (int r = 0; r < 4; ++r) {
          out[((size_t)t * BB + rg * RB + rq * 4 + r) * DD + dcol] =
              (acc[hh][nt][r] - mu[r]) * rs[r] * eg + eb;
          acc[hh][nt][r] = 0.f;
        }
      }
    __syncthreads();  // bar2: LDS(t+1) staged; parts consumed
  }
}

extern "C" void kernel_launch(void* const* d_in, const int* in_sizes, int n_in,
                              void* d_out, int out_size, void* d_ws, size_t ws_size,
                              hipStream_t stream) {
  const float* src = (const float*)d_in[0];
  const float* W = (const float*)d_in[1];
  const float* bias = (const float*)d_in[2];
  const float* gamma = (const float*)d_in[3];
  const float* beta = (const float*)d_in[4];
  float* out = (float*)d_out;
  u16* Wf = (u16*)d_ws;  // 256 KB repacked bf16 W fragments

  prep_w<<<64, 256, 0, stream>>>(W, Wf);
  lienet_main<<<(SS / GT) * 2, 512, 0, stream>>>(src, Wf, bias, gamma, beta, out);
}

// Round 4
// 283.178 us; speedup vs baseline: 2.1899x; 2.1899x over previous
//
#include <hip/hip_runtime.h>

#define SS 2048
#define BB 32
#define DD 1024
#define RB 16   // batch rows per block
#define GT 8    // t-steps per block

typedef unsigned short u16;
typedef unsigned int u32;
using f32x4 = __attribute__((ext_vector_type(4))) float;
using bf16x8 = __attribute__((ext_vector_type(8))) short;

__device__ __forceinline__ u16 f2bf(float x) {
  union { float f; u32 u; } c; c.f = x;
  u32 r = c.u + 0x7fffu + ((c.u >> 16) & 1u);
  return (u16)(r >> 16);
}
__device__ __forceinline__ float bf2f(u32 h) {
  union { u32 u; float f; } c; c.u = h << 16; return c.f;
}
// XOR swizzle for row-stride-2048B bf16 tiles (verified R1-R3): spreads
// cross-row same-col ds_read_b128 A-frag loads across banks; 16B chunks intact.
__device__ __forceinline__ int swzb(int row, int col) {
  return ((row << 11) + (col << 1)) ^ ((row & 7) << 4);
}
__device__ __forceinline__ void st8(u16* base, int row, int col, float4 a, float4 b) {
  uint4 pk;
  pk.x = (u32)f2bf(a.x) | ((u32)f2bf(a.y) << 16);
  pk.y = (u32)f2bf(a.z) | ((u32)f2bf(a.w) << 16);
  pk.z = (u32)f2bf(b.x) | ((u32)f2bf(b.y) << 16);
  pk.w = (u32)f2bf(b.z) | ((u32)f2bf(b.w) << 16);
  *reinterpret_cast<uint4*>(reinterpret_cast<char*>(base) + swzb(row, col)) = pk;
}
__device__ __forceinline__ void st8z(u16* base, int row, int col) {
  uint4 pk; pk.x = pk.y = pk.z = pk.w = 0u;
  *reinterpret_cast<uint4*>(reinterpret_cast<char*>(base) + swzb(row, col)) = pk;
}
__device__ __forceinline__ uint4 ld16(const u16* base, int row, int col) {
  return *reinterpret_cast<const uint4*>(reinterpret_cast<const char*>(base) + swzb(row, col));
}
__device__ __forceinline__ bf16x8 ld_afrag(const u16* base, int row, int col) {
  return *reinterpret_cast<const bf16x8*>(reinterpret_cast<const char*>(base) + swzb(row, col));
}
// tanh-form GELU, branch-free (v_exp_f32). |err| vs exact < ~3e-4.
__device__ __forceinline__ float gelu_f(float v) {
  const float u2 = 1.5957691216057308f * v * __builtin_fmaf(0.044715f, v * v, 1.0f);
  const float e = __expf(u2);
  const float th = 1.0f - 2.0f * __builtin_amdgcn_rcpf(e + 1.0f);
  return 0.5f * v * (1.0f + th);
}
// full-row LN stats: 16 elems/lane over a 64-lane wave (fp32 inputs).
__device__ __forceinline__ void rowstats(float4 a, float4 b, float4 c, float4 d,
                                         float& mu, float& rs) {
  float s1 = a.x + a.y + a.z + a.w + b.x + b.y + b.z + b.w +
             c.x + c.y + c.z + c.w + d.x + d.y + d.z + d.w;
  float s2 = a.x*a.x + a.y*a.y + a.z*a.z + a.w*a.w + b.x*b.x + b.y*b.y + b.z*b.z + b.w*b.w +
             c.x*c.x + c.y*c.y + c.z*c.z + c.w*c.w + d.x*d.x + d.y*d.y + d.z*d.z + d.w*d.w;
#pragma unroll
  for (int off = 32; off; off >>= 1) { s1 += __shfl_xor(s1, off); s2 += __shfl_xor(s2, off); }
  mu = s1 * (1.f / 1024.f);
  rs = rsqrtf(s2 * (1.f / 1024.f) - mu * mu + 1e-5f);
}

// W [H][128][64] f32 -> bf16 MFMA B-frags; gamma folded into the top (c) half.
// Wf[((h*4+ks)*4+nt)*64 + lane][j] = bf16( W'[h][ks*32+8*(lane>>4)+j][nt*16+(lane&15)] )
__global__ void prep_w2(const float* __restrict__ W, const float* __restrict__ gamma,
                        u16* __restrict__ Wf) {
  const int o = blockIdx.x * 256 + threadIdx.x;
  const int l = o & 63;
  const int tile = o >> 6;
  const int nt = tile & 3, ks = (tile >> 2) & 3, h = tile >> 4;
  const int d = nt * 16 + (l & 15);
  const int kbw = ks * 32 + 8 * (l >> 4);
  u16 v[8];
#pragma unroll
  for (int j = 0; j < 8; ++j) {
    const int k = kbw + j;
    float w = W[(h * 128 + k) * 64 + d];
    if (ks < 2) w *= gamma[h * 64 + k];   // top half multiplies LN'd values
    v[j] = f2bf(w);
  }
  uint4 pk;
  pk.x = (u32)v[0] | ((u32)v[1] << 16);
  pk.y = (u32)v[2] | ((u32)v[3] << 16);
  pk.z = (u32)v[4] | ((u32)v[5] << 16);
  pk.w = (u32)v[6] | ((u32)v[7] << 16);
  reinterpret_cast<uint4*>(Wf)[o] = pk;
}

// vg[d] = sum_k gamma[h*64+k]*W_top[k,d] ; bias2[d] = bias[d] + sum_k beta[..]*W_top[k,d]
__global__ void prep_v(const float* __restrict__ W, const float* __restrict__ gamma,
                       const float* __restrict__ beta, const float* __restrict__ bias,
                       float* __restrict__ vg, float* __restrict__ bias2) {
  const int d = blockIdx.x * 256 + threadIdx.x;   // 0..1023
  const int h = d >> 6, dd = d & 63;
  float sg = 0.f, sb = 0.f;
  for (int k = 0; k < 64; ++k) {
    const float w = W[(h * 128 + k) * 64 + dd];
    sg += gamma[h * 64 + k] * w;
    sb += beta[h * 64 + k] * w;
  }
  vg[d] = sg;
  bias2[d] = bias[d] + sb;
}

__global__ __launch_bounds__(1024, 4) void lienet_main(
    const float* __restrict__ src, const u16* __restrict__ Wf,
    const float* __restrict__ vg, const float* __restrict__ bias2,
    const float* __restrict__ bias, const float* __restrict__ gamma,
    const float* __restrict__ beta, float* __restrict__ out) {
  __shared__ __align__(16) u16 bufA[RB * DD];   // 32 KB: s_r * x(t-1), bf16
  __shared__ __align__(16) u16 bufB[RB * DD];   // 32 KB: x(t), bf16
  __shared__ float2 part[RB][17];               // final-LN partials (padded)
  __shared__ float pm[RB];                      // mu_r * s_r of x(t-1)

  const int bid = blockIdx.x;                   // 512 blocks = 256 t-chunks x 2 row-groups
  const int t0 = (bid >> 1) * GT;
  const int rg = bid & 1;
  const int tid = threadIdx.x;
  const int wave = tid >> 6;                    // = head h = staged row
  const int lane = tid & 63;
  const int cl = lane & 15;
  const int rq = lane >> 4;
  const int kb = rq * 8;
  const int c0 = lane * 8;
  const int h = wave;
  const int grow = rg * RB + wave;              // global batch row this wave owns

  // ---- W fragments -> registers (once per block; 64 VGPRs) ----
  uint4 wreg[4][4];
  const uint4* wfu = reinterpret_cast<const uint4*>(Wf);
#pragma unroll
  for (int ks = 0; ks < 4; ++ks)
#pragma unroll
    for (int nt = 0; nt < 4; ++nt)
      wreg[ks][nt] = wfu[((h * 4 + ks) * 4 + nt) * 64 + lane];
  float vgr[4], b2r[4];
#pragma unroll
  for (int nt = 0; nt < 4; ++nt) {
    const int d = h * 64 + nt * 16 + cl;
    vgr[nt] = vg[d];
    b2r[nt] = bias2[d];
  }

  // ---- prologue: stage x(t0) and scaled x(t0-1) ----
  float cur_mu, cur_s;   // stats of the row currently in bufB
  {
    const float* xp = src + ((size_t)t0 * BB + grow) * DD;
    float4 a0 = *reinterpret_cast<const float4*>(xp + c0);
    float4 a1 = *reinterpret_cast<const float4*>(xp + c0 + 4);
    float4 a2 = *reinterpret_cast<const float4*>(xp + 512 + c0);
    float4 a3 = *reinterpret_cast<const float4*>(xp + 512 + c0 + 4);
    rowstats(a0, a1, a2, a3, cur_mu, cur_s);
    st8(bufB, wave, c0, a0, a1);
    st8(bufB, wave, 512 + c0, a2, a3);
  }
  if (t0 == 0) {
    st8z(bufA, wave, c0);
    st8z(bufA, wave, 512 + c0);
    if (lane == 0) pm[wave] = 0.f;
  } else {
    const float* xp = src + ((size_t)(t0 - 1) * BB + grow) * DD;
    float4 a0 = *reinterpret_cast<const float4*>(xp + c0);
    float4 a1 = *reinterpret_cast<const float4*>(xp + c0 + 4);
    float4 a2 = *reinterpret_cast<const float4*>(xp + 512 + c0);
    float4 a3 = *reinterpret_cast<const float4*>(xp + 512 + c0 + 4);
    float pmu, ps;
    rowstats(a0, a1, a2, a3, pmu, ps);
    a0.x *= ps; a0.y *= ps; a0.z *= ps; a0.w *= ps;
    a1.x *= ps; a1.y *= ps; a1.z *= ps; a1.w *= ps;
    a2.x *= ps; a2.y *= ps; a2.z *= ps; a2.w *= ps;
    a3.x *= ps; a3.y *= ps; a3.z *= ps; a3.w *= ps;
    st8(bufA, wave, c0, a0, a1);
    st8(bufA, wave, 512 + c0, a2, a3);
    if (lane == 0) pm[wave] = pmu * ps;
  }
  __syncthreads();

  // ---- main loop ----
  for (int t = t0; t < t0 + GT; ++t) {
    const bool stage = (t + 1 < t0 + GT);
    float4 r0, r1, r2, r3;
    if (stage) {   // prefetch x(t+1): latency hides under this iter's work
      const float* xp = src + ((size_t)(t + 1) * BB + grow) * DD;
      r0 = *reinterpret_cast<const float4*>(xp + c0);
      r1 = *reinterpret_cast<const float4*>(xp + c0 + 4);
      r2 = *reinterpret_cast<const float4*>(xp + 512 + c0);
      r3 = *reinterpret_cast<const float4*>(xp + 512 + c0 + 4);
    }
    // MFMA: y = s*xprev @ (gamma.W_top) + x @ W_bot   (K=128 over 4 slices)
    f32x4 acc[4];
#pragma unroll
    for (int nt = 0; nt < 4; ++nt) acc[nt] = (f32x4){0.f, 0.f, 0.f, 0.f};
#pragma unroll
    for (int ks = 0; ks < 4; ++ks) {
      const u16* sb = (ks < 2) ? bufA : bufB;
      bf16x8 afr = ld_afrag(sb, cl, h * 64 + (ks & 1) * 32 + kb);
#pragma unroll
      for (int nt = 0; nt < 4; ++nt)
        acc[nt] = __builtin_amdgcn_mfma_f32_16x16x32_bf16(
            afr, *reinterpret_cast<bf16x8*>(&wreg[ks][nt]), acc[nt], 0, 0, 0);
    }
    // bias + mu-correction + GELU (in place)
    float pmv[4];
#pragma unroll
    for (int j = 0; j < 4; ++j) pmv[j] = pm[rq * 4 + j];
    const bool is0 = (t == 0);
#pragma unroll
    for (int nt = 0; nt < 4; ++nt) {
      const float bt = is0 ? bias[h * 64 + nt * 16 + cl] : b2r[nt];
#pragma unroll
      for (int j = 0; j < 4; ++j) {
        const float v = acc[nt][j] + bt - pmv[j] * vgr[nt];
        acc[nt][j] = gelu_f(v);
      }
    }
    // per-row partials for the output LN (this wave's 64 cols)
#pragma unroll
    for (int j = 0; j < 4; ++j) {
      float a = acc[0][j] + acc[1][j] + acc[2][j] + acc[3][j];
      float b = acc[0][j]*acc[0][j] + acc[1][j]*acc[1][j] +
                acc[2][j]*acc[2][j] + acc[3][j]*acc[3][j];
      a += __shfl_xor(a, 1); b += __shfl_xor(b, 1);
      a += __shfl_xor(a, 2); b += __shfl_xor(b, 2);
      a += __shfl_xor(a, 4); b += __shfl_xor(b, 4);
      a += __shfl_xor(a, 8); b += __shfl_xor(b, 8);
      if (cl == 0) part[rq * 4 + j][h] = make_float2(a, b);
    }
    __syncthreads();   // bar1: MFMA reads done; partials visible

    // merge LN stats; write out(t)
    float eg[4], eb[4];
#pragma unroll
    for (int nt = 0; nt < 4; ++nt) {
      const int d = h * 64 + nt * 16 + cl;
      eg[nt] = gamma[d];
      eb[nt] = beta[d];
    }
#pragma unroll
    for (int j = 0; j < 4; ++j) {
      const int row = rq * 4 + j;
      float2 pe = part[row][cl];
      float a = pe.x, b = pe.y;
      a += __shfl_xor(a, 1); b += __shfl_xor(b, 1);
      a += __shfl_xor(a, 2); b += __shfl_xor(b, 2);
      a += __shfl_xor(a, 4); b += __shfl_xor(b, 4);
      a += __shfl_xor(a, 8); b += __shfl_xor(b, 8);
      const float mu = a * (1.f / 1024.f);
      const float rs = rsqrtf(b * (1.f / 1024.f) - mu * mu + 1e-5f);
      float* op = out + ((size_t)t * BB + rg * RB + row) * DD;
#pragma unroll
      for (int nt = 0; nt < 4; ++nt)
        op[h * 64 + nt * 16 + cl] = (acc[nt][j] - mu) * rs * eg[nt] + eb[nt];
    }
    // rescale x(t) -> s*x(t) into bufA, restage x(t+1) into bufB (wave-local row)
    if (stage) {
      const float sc = cur_s;
      uint4 g0 = ld16(bufB, wave, c0);
      uint4 g1 = ld16(bufB, wave, 512 + c0);
      float4 a0, a1, a2, a3;
      a0.x = bf2f(g0.x & 0xffffu) * sc; a0.y = bf2f(g0.x >> 16) * sc;
      a0.z = bf2f(g0.y & 0xffffu) * sc; a0.w = bf2f(g0.y >> 16) * sc;
      a1.x = bf2f(g0.z & 0xffffu) * sc; a1.y = bf2f(g0.z >> 16) * sc;
      a1.z = bf2f(g0.w & 0xffffu) * sc; a1.w = bf2f(g0.w >> 16) * sc;
      a2.x = bf2f(g1.x & 0xffffu) * sc; a2.y = bf2f(g1.x >> 16) * sc;
      a2.z = bf2f(g1.y & 0xffffu) * sc; a2.w = bf2f(g1.y >> 16) * sc;
      a3.x = bf2f(g1.z & 0xffffu) * sc; a3.y = bf2f(g1.z >> 16) * sc;
      a3.z = bf2f(g1.w & 0xffffu) * sc; a3.w = bf2f(g1.w >> 16) * sc;
      st8(bufA, wave, c0, a0, a1);
      st8(bufA, wave, 512 + c0, a2, a3);
      if (lane == 0) pm[wave] = cur_mu * cur_s;   // stats of x(t), now the "prev"
      rowstats(r0, r1, r2, r3, cur_mu, cur_s);    // stats of x(t+1)
      st8(bufB, wave, c0, r0, r1);
      st8(bufB, wave, 512 + c0, r2, r3);
    }
    __syncthreads();   // bar2: new tiles/pm staged
  }
}

extern "C" void kernel_launch(void* const* d_in, const int* in_sizes, int n_in,
                              void* d_out, int out_size, void* d_ws, size_t ws_size,
                              hipStream_t stream) {
  const float* src = (const float*)d_in[0];
  const float* W = (const float*)d_in[1];
  const float* bias = (const float*)d_in[2];
  const float* gamma = (const float*)d_in[3];
  const float* beta = (const float*)d_in[4];
  float* out = (float*)d_out;
  u16* Wf = (u16*)d_ws;                               // 256 KB
  float* vgp = (float*)((char*)d_ws + 262144);        // 4 KB
  float* b2p = vgp + 1024;                            // 4 KB

  prep_w2<<<64, 256, 0, stream>>>(W, gamma, Wf);
  prep_v<<<4, 256, 0, stream>>>(W, gamma, beta, bias, vgp, b2p);
  lienet_main<<<(SS / GT) * 2, 1024, 0, stream>>>(src, Wf, vgp, b2p, bias, gamma, beta, out);
}